// Round 10
// baseline (10.218 us; speedup 1.0000x reference)
//
#include <hip/hip_runtime.h>

#define NK 8
#define NR 32
#define NF 16
#define NB 32768
#define LOG2E 1.4426950408889634f

typedef _Float16 f16x2  __attribute__((ext_vector_type(2)));
typedef _Float16 f16x8  __attribute__((ext_vector_type(8)));
typedef float    f32x16 __attribute__((ext_vector_type(16)));

union h8u { f16x2 h2[4]; f16x8 v; };

__device__ __forceinline__ f16x2 pk_cvt(float a, float b) {
    auto t = __builtin_amdgcn_cvt_pkrtz(a, b);   // __fp16 ext_vector(2): same bits
    f16x2 r;
    __builtin_memcpy(&r, &t, sizeof(r));
    return r;
}

// One fused kernel. Block = 512 = 8 waves; wave k <-> branch k, 64 batch cols/block.
// 32x32x16 f16 MFMA, rules = 32 rows in one tile:
//   S1[r,b] = sum_f A_f x^2 + B_f x (+C_r); S2[r,b] = sum_f W_f x (+bias_r)
// Lane map: m = lane&31 (rule row / batch col), h = lane>>5 (features h*8..h*8+7).
// C/D: col = lane&31, row = (reg&3) + 8*(reg>>2) + 4*h   [HW-verified, R7]
__global__ __launch_bounds__(512, 4) void hfnn_fused(
    const float* __restrict__ data, const float* __restrict__ mu,
    const float* __restrict__ sg,   const float* __restrict__ w3,
    const float* __restrict__ w5,   const float* __restrict__ b5,
    float* __restrict__ out)
{
    __shared__ float tl[NK][64];          // tsk[k][b]

    const int lane = threadIdx.x & 63;
    const int k    = threadIdx.x >> 6;    // wave id == branch
    const int h    = lane >> 5;
    const int m    = lane & 31;

    // ---- x prefetch first: HBM latency hides under the fold ----
    const int bbase = blockIdx.x * 64;
    float4 xv[2][2];
#pragma unroll
    for (int tau = 0; tau < 2; ++tau) {
        const float* xp = data + ((size_t)k * NB + (bbase + tau * 32 + m)) * NF + h * 8;
        xv[tau][0] = reinterpret_cast<const float4*>(xp)[0];
        xv[tau][1] = reinterpret_cast<const float4*>(xp)[1];
    }

    // ---- fold: lane covers rule m, features h*8..h*8+7 (zero redundancy) ----
    const float* sp = sg + ((size_t)(k * NR + m) * NF + h * 8);
    const float* mp = mu + ((size_t)(k * NR + m) * NF + h * 8);
    float4 s0 = reinterpret_cast<const float4*>(sp)[0];
    float4 s1 = reinterpret_cast<const float4*>(sp)[1];
    float4 m0 = reinterpret_cast<const float4*>(mp)[0];
    float4 m1 = reinterpret_cast<const float4*>(mp)[1];
    float sv[8] = {s0.x,s0.y,s0.z,s0.w,s1.x,s1.y,s1.z,s1.w};
    float mv[8] = {m0.x,m0.y,m0.z,m0.w,m1.x,m1.y,m1.z,m1.w};

    f16x8 frA, frB, frW;
    float cp = 0.f;
#pragma unroll
    for (int j = 0; j < 8; ++j) {
        float a = __fdividef(-(LOG2E * 0.5f), sv[j] * sv[j]);
        frA[j] = (_Float16)a;
        frB[j] = (_Float16)(-2.0f * a * mv[j]);
        cp = fmaf(a * mv[j], mv[j], cp);
    }
    float C = cp + __shfl_xor(cp, 32);    // full 16-feature sum for rule m

    const float* wp = w3 + (size_t)(k * NR + m) * (NF + 1) + h * 8;
#pragma unroll
    for (int j = 0; j < 8; ++j) frW[j] = (_Float16)wp[j];
    float bias = w3[(size_t)(k * NR + m) * (NF + 1) + NF];

    // ---- one-time redistribution of C/bias into accumulator-init layout ----
    f32x16 c1i, c2i;
#pragma unroll
    for (int reg = 0; reg < 16; ++reg) {
        const int row = (reg & 3) + 8 * (reg >> 2) + 4 * h;
        c1i[reg] = __shfl(C, row);
        c2i[reg] = __shfl(bias, row);
    }

    // ---- main: 2 batch tiles of 32 cols, 3 MFMA each ----
#pragma unroll
    for (int tau = 0; tau < 2; ++tau) {
        float4 v0 = xv[tau][0], v1 = xv[tau][1];
        h8u X, X2;
        X.h2[0] = pk_cvt(v0.x, v0.y);
        X.h2[1] = pk_cvt(v0.z, v0.w);
        X.h2[2] = pk_cvt(v1.x, v1.y);
        X.h2[3] = pk_cvt(v1.z, v1.w);
        X2.h2[0] = X.h2[0] * X.h2[0];     // v_pk_mul_f16
        X2.h2[1] = X.h2[1] * X.h2[1];
        X2.h2[2] = X.h2[2] * X.h2[2];
        X2.h2[3] = X.h2[3] * X.h2[3];

        f32x16 s1a = __builtin_amdgcn_mfma_f32_32x32x16_f16(frA, X2.v, c1i, 0, 0, 0);
        s1a        = __builtin_amdgcn_mfma_f32_32x32x16_f16(frB, X.v,  s1a, 0, 0, 0);
        f32x16 s2a = __builtin_amdgcn_mfma_f32_32x32x16_f16(frW, X.v,  c2i, 0, 0, 0);

        float num = 0.f, den = 0.f;
#pragma unroll
        for (int reg = 0; reg < 16; ++reg) {
            float e = __builtin_amdgcn_exp2f(s1a[reg]);
            den += e;
            num = fmaf(e, s2a[reg], num);
        }
        num += __shfl_xor(num, 32);       // combine the two rule-halves
        den += __shfl_xor(den, 32);
        if (h == 0) tl[k][tau * 32 + m] = __fdividef(num, den);
    }
    __syncthreads();

    if (threadIdx.x < 64) {               // wave 0: branch combine + 2-class softmax
        float l0 = b5[0], l1 = b5[1];
#pragma unroll
        for (int kk = 0; kk < NK; ++kk) {
            float t = tl[kk][lane];
            l0 = fmaf(t, w5[kk],      l0);
            l1 = fmaf(t, w5[NK + kk], l1);
        }
        float mx = fmaxf(l0, l1);
        float e0 = __expf(l0 - mx);
        float e1 = __expf(l1 - mx);
        float inv = __fdividef(1.f, e0 + e1);
        *reinterpret_cast<float2*>(out + (size_t)(bbase + lane) * 2) =
            make_float2(e0 * inv, e1 * inv);
    }
}

extern "C" void kernel_launch(void* const* d_in, const int* in_sizes, int n_in,
                              void* d_out, int out_size, void* d_ws, size_t ws_size,
                              hipStream_t stream) {
    const float* data = (const float*)d_in[0];
    const float* mu   = (const float*)d_in[1];
    const float* sg   = (const float*)d_in[2];
    const float* w3   = (const float*)d_in[3];
    const float* w5   = (const float*)d_in[4];
    const float* b5   = (const float*)d_in[5];
    float* out = (float*)d_out;

    hfnn_fused<<<NB / 64, 512, 0, stream>>>(data, mu, sg, w3, w5, b5, out);
}

// Round 11
// 9.495 us; speedup vs baseline: 1.0761x; 1.0761x over previous
//
#include <hip/hip_runtime.h>

#define NK 8
#define NR 32
#define NF 16
#define NB 32768
#define LOG2E 1.4426950408889634f

typedef _Float16 f16x8  __attribute__((ext_vector_type(8)));
typedef float    f32x16 __attribute__((ext_vector_type(16)));

// One fused kernel. Block = 512 = 8 waves; wave k <-> branch k, 64 batch elems/block.
// 32x32x16 f16 MFMA: rules = 32 rows in ONE tile.
//   S1[r,b] = sum_f A_f x^2 + B_f x (+C_r) : mfma(frA, x^2-frag, Cinit) then mfma(frB, x-frag, .)
//   S2[r,b] = sum_f W_f x           (+bias): mfma(frW, x-frag, BiasInit)
// Lane map: m = lane&31 (A-row = rule, B-col = batch col), h = lane>>5 (features h*8..h*8+7).
// C/D: col = lane&31, row = (reg&3) + 8*(reg>>2) + 4*h   [HW-verified, R7]
__global__ __launch_bounds__(512, 4) void hfnn_fused(
    const float* __restrict__ data, const float* __restrict__ mu,
    const float* __restrict__ sg,   const float* __restrict__ w3,
    const float* __restrict__ w5,   const float* __restrict__ b5,
    float* __restrict__ out)
{
    __shared__ float tl[NK][64];          // tsk[k][b]

    const int lane = threadIdx.x & 63;
    const int k    = threadIdx.x >> 6;    // wave id == branch
    const int h    = lane >> 5;           // K-subhalf / rule-half selector
    const int m    = lane & 31;           // rule row (A) / batch col (B)

    // ---- x loads first: HBM latency hides under the fold ----
    const int bbase = blockIdx.x * 64;
    float4 xv[2][2];
#pragma unroll
    for (int tau = 0; tau < 2; ++tau) {
        const float* xp = data + ((size_t)k * NB + (bbase + tau * 32 + m)) * NF + h * 8;
        xv[tau][0] = reinterpret_cast<const float4*>(xp)[0];
        xv[tau][1] = reinterpret_cast<const float4*>(xp)[1];
    }

    // ---- fold: each lane covers rule m, features h*8..h*8+7 (zero redundancy) ----
    const float* sp = sg + ((size_t)(k * NR + m) * NF + h * 8);
    const float* mp = mu + ((size_t)(k * NR + m) * NF + h * 8);
    float4 s0 = reinterpret_cast<const float4*>(sp)[0];
    float4 s1 = reinterpret_cast<const float4*>(sp)[1];
    float4 m0 = reinterpret_cast<const float4*>(mp)[0];
    float4 m1 = reinterpret_cast<const float4*>(mp)[1];
    float sv[8] = {s0.x,s0.y,s0.z,s0.w,s1.x,s1.y,s1.z,s1.w};
    float mv[8] = {m0.x,m0.y,m0.z,m0.w,m1.x,m1.y,m1.z,m1.w};

    f16x8 frA, frB, frW;
    float cp = 0.f;
#pragma unroll
    for (int j = 0; j < 8; ++j) {
        float a = __fdividef(-(LOG2E * 0.5f), sv[j] * sv[j]);
        frA[j] = (_Float16)a;
        frB[j] = (_Float16)(-2.0f * a * mv[j]);
        cp = fmaf(a * mv[j], mv[j], cp);
    }
    float C = cp + __shfl_xor(cp, 32);    // full sum over 16 features for rule m

    const float* wp = w3 + (size_t)(k * NR + m) * (NF + 1) + h * 8;
#pragma unroll
    for (int j = 0; j < 8; ++j) frW[j] = (_Float16)wp[j];   // rows stride 17: scalar loads, L2-hot
    float bias = w3[(size_t)(k * NR + m) * (NF + 1) + NF];

    // ---- redistribute C/bias into accumulator-init layout (one-time, 32 shuffles) ----
    f32x16 c1i, c2i;
#pragma unroll
    for (int reg = 0; reg < 16; ++reg) {
        const int row = (reg & 3) + 8 * (reg >> 2) + 4 * h;
        c1i[reg] = __shfl(C, row);
        c2i[reg] = __shfl(bias, row);
    }

    // ---- main: 2 batch tiles of 32 cols, 3 MFMA each ----
#pragma unroll
    for (int tau = 0; tau < 2; ++tau) {
        float4 v0 = xv[tau][0], v1 = xv[tau][1];
        f16x8 bf2, bf1;
        bf2[0] = (_Float16)v0.x; bf2[1] = (_Float16)v0.y;
        bf2[2] = (_Float16)v0.z; bf2[3] = (_Float16)v0.w;
        bf2[4] = (_Float16)v1.x; bf2[5] = (_Float16)v1.y;
        bf2[6] = (_Float16)v1.z; bf2[7] = (_Float16)v1.w;
        bf1[0] = (_Float16)(v0.x*v0.x); bf1[1] = (_Float16)(v0.y*v0.y);
        bf1[2] = (_Float16)(v0.z*v0.z); bf1[3] = (_Float16)(v0.w*v0.w);
        bf1[4] = (_Float16)(v1.x*v1.x); bf1[5] = (_Float16)(v1.y*v1.y);
        bf1[6] = (_Float16)(v1.z*v1.z); bf1[7] = (_Float16)(v1.w*v1.w);

        f32x16 s1a = __builtin_amdgcn_mfma_f32_32x32x16_f16(frA, bf1, c1i, 0, 0, 0);
        s1a        = __builtin_amdgcn_mfma_f32_32x32x16_f16(frB, bf2, s1a, 0, 0, 0);
        f32x16 s2a = __builtin_amdgcn_mfma_f32_32x32x16_f16(frW, bf2, c2i, 0, 0, 0);

        float num = 0.f, den = 0.f;
#pragma unroll
        for (int reg = 0; reg < 16; ++reg) {
            float e = __builtin_amdgcn_exp2f(s1a[reg]);
            den += e;
            num = fmaf(e, s2a[reg], num);
        }
        num += __shfl_xor(num, 32);       // combine the two rule-halves
        den += __shfl_xor(den, 32);
        if (h == 0) tl[k][tau * 32 + m] = __fdividef(num, den);
    }
    __syncthreads();

    if (threadIdx.x < 64) {               // wave 0: branch combine + 2-class softmax
        float l0 = b5[0], l1 = b5[1];
#pragma unroll
        for (int kk = 0; kk < NK; ++kk) {
            float t = tl[kk][lane];
            l0 = fmaf(t, w5[kk],      l0);
            l1 = fmaf(t, w5[NK + kk], l1);
        }
        float mx = fmaxf(l0, l1);
        float e0 = __expf(l0 - mx);
        float e1 = __expf(l1 - mx);
        float inv = __fdividef(1.f, e0 + e1);
        *reinterpret_cast<float2*>(out + (size_t)(blockIdx.x * 64 + lane) * 2) =
            make_float2(e0 * inv, e1 * inv);
    }
}

extern "C" void kernel_launch(void* const* d_in, const int* in_sizes, int n_in,
                              void* d_out, int out_size, void* d_ws, size_t ws_size,
                              hipStream_t stream) {
    const float* data = (const float*)d_in[0];
    const float* mu   = (const float*)d_in[1];
    const float* sg   = (const float*)d_in[2];
    const float* w3   = (const float*)d_in[3];
    const float* w5   = (const float*)d_in[4];
    const float* b5   = (const float*)d_in[5];
    float* out = (float*)d_out;

    hfnn_fused<<<NB / 64, 512, 0, stream>>>(data, mu, sg, w3, w5, b5, out);
}